// Round 8
// baseline (632.991 us; speedup 1.0000x reference)
//
#include <hip/hip_runtime.h>
#include <math.h>

// Problem constants
#define NB   256
#define TT   36
#define FF   50
#define PP   80
#define KK   161
#define NITER 100
#define LAMB 0.1f

#define CODE_SZ (NB*KK*FF)          // 2,060,800
#define D_OFF   CODE_SZ
#define R_OFF   (CODE_SZ + TT*KK)

// ws float layout:
// [0]=linv (k_build2), [1]=wn^2 accumulator, [16..79]=ssq partials
#define WSA1 128                    // D image   [Mt1:3][kt:6][h:2][512] f16 = 9216 fl
#define WSA2 (WSA1 + 9216)          // D^T image [Mt2:6][kt:3][h:2][512] f16 = 9216 fl
#define WSG  (WSA2 + 9216)          // G = -DtD/L [Mt2:6][kt:11][h:2][512] f16 = 33792 fl
#define WSDTD (WSG + 33792)         // raw DtD [176][176] floats

typedef _Float16 half8  __attribute__((ext_vector_type(8)));
typedef _Float16 half16v __attribute__((ext_vector_type(16)));
typedef float f32x4  __attribute__((ext_vector_type(4)));
typedef float f32x16 __attribute__((ext_vector_type(16)));
#define MFMA_16(A,B,C) __builtin_amdgcn_mfma_f32_16x16x32_f16(A,B,C,0,0,0)
#define MFMA_32(A,B,C) __builtin_amdgcn_mfma_f32_32x32x16_f16(A,B,C,0,0,0)

// ---------------------------------------------------------------------------
// K1 (grid 64): build D (blk0 -> d_out), raw DtD -> ws, ssq partials,
// pack f16 hi/lo images for D (16x16x32 A-op) and D^T (32x32x16 A-op).
__global__ __launch_bounds__(256) void k_build1(const float* __restrict__ rr,
                                                const float* __restrict__ th,
                                                float* __restrict__ out,
                                                float* __restrict__ ws) {
    __shared__ float Dl[TT*KK];
    __shared__ float red[256];
    int tid = threadIdx.x, b = blockIdx.x;
    for (int e = tid; e < TT*KK; e += 256) {
        int t = e / KK, k = e % KK;
        float v;
        if (k == 0) v = 1.f;
        else if (k <= PP) { int p = k - 1;     v = powf(rr[p], (float)t) * cosf((float)t * th[p]); }
        else              { int p = k - 1 - PP; v = powf(rr[p], (float)t) * sinf((float)t * th[p]); }
        Dl[e] = v;
        if (b == 0) out[D_OFF + e] = v;
    }
    __syncthreads();
    float ssq = 0.f;
    for (int p = b*256 + tid; p < KK*KK; p += 64*256) {
        int k1 = p / KK, k2 = p % KK;
        float s = 0.f;
        for (int t = 0; t < TT; ++t) s += Dl[t*KK + k1] * Dl[t*KK + k2];
        ws[WSDTD + k1*176 + k2] = s;
        ssq += s * s;
    }
    red[tid] = ssq;
    __syncthreads();
    for (int off = 128; off > 0; off >>= 1) {
        if (tid < off) red[tid] += red[tid + off];
        __syncthreads();
    }
    if (tid == 0) { ws[16 + b] = red[0]; if (b == 0) ws[1] = 0.f; }

    // A1 (D): lane l holds A[m=l&15][k=8*(l>>4)+i] per 16x16x32 tile
    _Float16* a1 = (_Float16*)(ws + WSA1);
    for (int e = b*256 + tid; e < 3*6*2*512; e += 64*256) {
        int fp = e & 511, r = e >> 9;       // r = (Mt1*6+kt)*2 + h
        int h = r & 1, mk = r >> 1;
        int l = fp >> 3, i = fp & 7;
        int t = (mk / 6) * 16 + (l & 15);
        int j = (mk % 6) * 32 + ((l >> 4) << 3) + i;
        float v = (t < TT && j < KK) ? Dl[t*KK + j] : 0.f;
        _Float16 hi = (_Float16)v;
        a1[e] = h ? (_Float16)(v - (float)hi) : hi;
    }
    // A2 (D^T): lane l holds A[m=l&31][k=8*(l>>5)+i] per 32x32x16 tile
    _Float16* a2 = (_Float16*)(ws + WSA2);
    for (int e = b*256 + tid; e < 6*3*2*512; e += 64*256) {
        int fp = e & 511, r = e >> 9;       // r = (Mt2*3+kt)*2 + h
        int h = r & 1, mk = r >> 1;
        int l = fp >> 3, i = fp & 7;
        int m = (mk / 3) * 32 + (l & 31);
        int t = (mk % 3) * 16 + ((l >> 5) << 3) + i;
        float v = (m < KK && t < TT) ? Dl[t*KK + m] : 0.f;
        _Float16 hi = (_Float16)v;
        a2[e] = h ? (_Float16)(v - (float)hi) : hi;
    }
}

// ---------------------------------------------------------------------------
// K2 (grid 64): linv from partials; pack G = -DtD/L (NO identity; the I-term
// is applied in fp32 registers) as 32x32x16 A-operand image, hi/lo split.
__global__ __launch_bounds__(256) void k_build2(float* __restrict__ ws) {
    int tid = threadIdx.x, b = blockIdx.x;
    float ssum = 0.f;
    #pragma unroll
    for (int i = 0; i < 64; ++i) ssum += ws[16 + i];
    float linv = rsqrtf(ssum);
    if (b == 0 && tid == 0) ws[0] = linv;
    _Float16* ag = (_Float16*)(ws + WSG);
    for (int e = b*256 + tid; e < 6*11*2*512; e += 64*256) {
        int fp = e & 511, r = e >> 9;       // r = (Mt2*11+kt)*2 + h
        int h = r & 1, mk = r >> 1;
        int kt = mk % 11, Mt2 = mk / 11;
        int l = fp >> 3, i = fp & 7;
        int m = Mt2*32 + (l & 31);
        int k = kt*16 + ((l >> 5) << 3) + i;
        float v = 0.f;
        if (m < KK && k < KK) v = -ws[WSDTD + m*176 + k] * linv;
        _Float16 hi = (_Float16)v;
        ag[e] = h ? (_Float16)(v - (float)hi) : hi;
    }
}

// ---------------------------------------------------------------------------
// K3: fused FISTA, I-split Gram form: ay = y + G f16(y), G = -DtD/L.
// grid 256 (one n per block), 768 threads = 12 waves; wave = (Mt2 = w>>1,
// nh = w&1) for the single 32x32x16 GEMM, K = 176 (11 kt), G hi/lo in
// registers (2-term: exact for f16-quantized y); y fp32 kept in registers
// (quantization error passes only through G, not through I).
// y images double-buffered in LDS -> ONE barrier per iteration.
// EDGE GUARD: k >= 176 lanes (Mt2=5, g>=2) must NOT write the y image
// (kt_w would be 11 -> out of image; R7's OOB corruption bug).
__global__ __launch_bounds__(768, 3) void k_fista(float* __restrict__ ws,
                                                  const float* __restrict__ x,
                                                  float* __restrict__ out,
                                                  int phase) {
    __shared__ _Float16 S[2*11*2*512];   // 45,056 B: [buf:2][kt:11][nh:2][512]
    int tid = threadIdx.x;
    int w = tid >> 6, l = tid & 63;
    int n = blockIdx.x;
    int Mt2 = w >> 1, nh = w & 1;
    int nloc = l & 31, s5 = l >> 5;
    int fcol = nh*32 + nloc;
    float linv = ws[0];

    // ---- stage f16(x) -> XB (32x32x16 B-frag image over t; overlay on buf1)
    _Float16* XB = S + 11*2*512;
    const float* xb = x + n*TT*FF;
    for (int e = tid; e < 3072; e += 768) {
        int t = e >> 6, c64 = e & 63;
        float v = (t < TT && c64 < FF) ? xb[t*FF + c64] : 0.f;
        int nh2 = c64 >> 5, c = c64 & 31;
        int kt = t >> 4, kk = t & 15;
        int ofs = ((((kk >> 3) << 5) + c) << 3) + (kk & 7);
        XB[((nh2*3 + kt) << 9) + ofs] = (_Float16)v;
    }
    __syncthreads();

    // ---- head GEMM2: acc = D^T @ f16(x)
    f32x16 acc;
    #pragma unroll
    for (int r = 0; r < 16; ++r) acc[r] = 0.f;
    {
        const _Float16* a2g = (const _Float16*)(ws + WSA2);
        #pragma unroll
        for (int kt = 0; kt < 3; ++kt) {
            half8 ah = *(const half8*)(a2g + ((((Mt2*3 + kt)*2 + 0) << 9) + (l << 3)));
            half8 al = *(const half8*)(a2g + ((((Mt2*3 + kt)*2 + 1) << 9) + (l << 3)));
            half8 bh = *(const half8*)&XB[((nh*3 + kt) << 9) + (l << 3)];
            acc = MFMA_32(ah, bh, acc);
            acc = MFMA_32(al, bh, acc);
        }
    }

    // ---- peeled iteration 0: x1 = shrink(c), y1 = x1 -> buf0
    float cv[4][4], xo[4][4], yo[4][4];
    half16v wlh;
    {
        float wl0 = LAMB * linv;
        float fac = 0.f;
        if (phase) fac = (float)KK * LAMB * linv * rsqrtf(ws[1]);
        #pragma unroll
        for (int g = 0; g < 4; ++g) {
            int k0 = Mt2*32 + 8*g + 4*s5;
            union { unsigned long long u; _Float16 hh[4]; } yh;
            #pragma unroll
            for (int j = 0; j < 4; ++j) {
                int k = k0 + j;
                float c_ = 0.f, wl = 0.f;
                if (k < KK && fcol < FF) {
                    c_ = linv * acc[g*4 + j];
                    if (phase) {
                        float prev = out[(size_t)n*KK*FF + k*FF + fcol];
                        wl = fac / (fabsf(prev) + 0.01f);
                    } else wl = wl0;
                }
                cv[g][j] = c_;
                wlh[g*4 + j] = (_Float16)wl;
                float v = c_;
                float xn = v - fminf(fmaxf(v, -wl), wl);
                xo[g][j] = xn; yo[g][j] = xn;
                yh.hh[j] = (_Float16)xn;
            }
            int kt_w = 2*Mt2 + (g >> 1);
            if (kt_w < 11) {   // edge guard: k>=176 has no image slot
                int lofs = ((((g & 1) << 5) + nloc) << 3) + (s5 << 2);
                *(unsigned long long*)&S[(((0*11 + kt_w)*2 + nh) << 9) + lofs] = yh.u;
            }
        }
    }
    __syncthreads();

    // ---- G fragments -> registers (after head, to cap peak pressure)
    const _Float16* agp = (const _Float16*)(ws + WSG);
    half8 ag[11][2];
    #pragma unroll
    for (int kt = 0; kt < 11; ++kt) {
        ag[kt][0] = *(const half8*)(agp + ((((Mt2*11 + kt)*2 + 0) << 9) + (l << 3)));
        ag[kt][1] = *(const half8*)(agp + ((((Mt2*11 + kt)*2 + 1) << 9) + (l << 3)));
    }

    float t_old = 0.5f * (1.f + sqrtf(5.f));
    for (int it = 1; it < NITER; ++it) {
        int rbuf = (it - 1) & 1, wbuf = it & 1;
        // ---- single GEMM: acc = G @ f16(y)  (2-term, exact for f16 y)
        #pragma unroll
        for (int r = 0; r < 16; ++r) acc[r] = 0.f;
        #pragma unroll
        for (int kt = 0; kt < 11; ++kt) {
            half8 bh = *(const half8*)&S[(((rbuf*11 + kt)*2 + nh) << 9) + (l << 3)];
            acc = MFMA_32(ag[kt][0], bh, acc);
            acc = MFMA_32(ag[kt][1], bh, acc);
        }
        // ---- epilogue: ay = yo + acc; shrink via med3; momentum; y -> wbuf
        float t_new = 0.5f * (1.f + sqrtf(1.f + 4.f*t_old*t_old));
        float beta = (t_old - 1.f) / t_new;
        t_old = t_new;
        #pragma unroll
        for (int g = 0; g < 4; ++g) {
            union { unsigned long long u; _Float16 hh[4]; } yh;
            #pragma unroll
            for (int j = 0; j < 4; ++j) {
                float wl = (float)wlh[g*4 + j];
                float v = yo[g][j] + acc[g*4 + j] + cv[g][j];
                float xn = v - fminf(fmaxf(v, -wl), wl);
                float yn = fmaf(beta, xn - xo[g][j], xn);
                xo[g][j] = xn; yo[g][j] = yn;
                yh.hh[j] = (_Float16)yn;
            }
            int kt_w = 2*Mt2 + (g >> 1);
            if (kt_w < 11) {   // edge guard
                int lofs = ((((g & 1) << 5) + nloc) << 3) + (s5 << 2);
                *(unsigned long long*)&S[(((wbuf*11 + kt_w)*2 + nh) << 9) + lofs] = yh.u;
            }
        }
        __syncthreads();
    }

    // ---- store final code
    #pragma unroll
    for (int g = 0; g < 4; ++g) {
        int k0 = Mt2*32 + 8*g + 4*s5;
        #pragma unroll
        for (int j = 0; j < 4; ++j) {
            int k = k0 + j;
            if (k < KK && fcol < FF)
                out[(size_t)n*KK*FF + k*FF + fcol] = xo[g][j];
        }
    }

    if (!phase) {
        // ---- fused wnorm
        float s = 0.f;
        #pragma unroll
        for (int g = 0; g < 4; ++g) {
            int k0 = Mt2*32 + 8*g + 4*s5;
            #pragma unroll
            for (int j = 0; j < 4; ++j) {
                if (k0 + j < KK && fcol < FF) {
                    float wn = 1.f / (fabsf(xo[g][j]) + 0.01f);
                    s += wn * wn;
                }
            }
        }
        #pragma unroll
        for (int off = 32; off > 0; off >>= 1) s += __shfl_down(s, off);
        float* red = (float*)S;
        if (l == 0) red[w] = s;
        __syncthreads();
        if (tid == 0) {
            float t = 0.f;
            #pragma unroll
            for (int i = 0; i < 12; ++i) t += red[i];
            atomicAdd(&ws[1], t);
        }
    } else {
        // ---- fused reconst: f16(code) into 16x16x32 B image at S, GEMM1, store
        int cl = l & 15, q = l >> 4;
        int nt16 = nh*2 + (nloc >> 4);
        #pragma unroll
        for (int g = 0; g < 4; ++g) {
            union { unsigned long long u; _Float16 hh[4]; } yh;
            #pragma unroll
            for (int j = 0; j < 4; ++j) yh.hh[j] = (_Float16)xo[g][j];
            int yofs = ((g*16 + cl) << 3) + (s5 << 2);
            *(unsigned long long*)&S[((nt16*6 + Mt2) << 9) + yofs] = yh.u;
        }
        __syncthreads();
        const _Float16* a1g = (const _Float16*)(ws + WSA1);
        int Mt1 = w >> 2, nt1 = w & 3;
        f32x4 za = {0.f,0.f,0.f,0.f}, zb = {0.f,0.f,0.f,0.f};
        #pragma unroll
        for (int kt = 0; kt < 6; ++kt) {
            half8 ah = *(const half8*)(a1g + ((((Mt1*6 + kt)*2 + 0) << 9) + (l << 3)));
            half8 al = *(const half8*)(a1g + ((((Mt1*6 + kt)*2 + 1) << 9) + (l << 3)));
            half8 bh = *(const half8*)&S[((nt1*6 + kt) << 9) + (l << 3)];
            za = MFMA_16(ah, bh, za);
            zb = MFMA_16(al, bh, zb);
        }
        f32x4 zz = za + zb;
        int fcol2 = nt1*16 + cl;
        #pragma unroll
        for (int r = 0; r < 4; ++r) {
            int t = Mt1*16 + q*4 + r;
            if (t < TT && fcol2 < FF)
                out[R_OFF + (size_t)n*TT*FF + t*FF + fcol2] = zz[r];
        }
    }
}

// ---------------------------------------------------------------------------
extern "C" void kernel_launch(void* const* d_in, const int* in_sizes, int n_in,
                              void* d_out, int out_size, void* d_ws, size_t ws_size,
                              hipStream_t stream) {
    const float* x  = (const float*)d_in[0];
    const float* rr = (const float*)d_in[1];
    const float* th = (const float*)d_in[2];
    float* out = (float*)d_out;
    float* ws  = (float*)d_ws;

    hipLaunchKernelGGL(k_build1, dim3(64), dim3(256), 0, stream, rr, th, out, ws);
    hipLaunchKernelGGL(k_build2, dim3(64), dim3(256), 0, stream, ws);
    hipLaunchKernelGGL(k_fista,  dim3(NB), dim3(768), 0, stream, ws, x, out, 0);
    hipLaunchKernelGGL(k_fista,  dim3(NB), dim3(768), 0, stream, ws, x, out, 1);
}

// Round 9
// 567.364 us; speedup vs baseline: 1.1157x; 1.1157x over previous
//
#include <hip/hip_runtime.h>
#include <math.h>

// Problem constants
#define NB   256
#define TT   36
#define FF   50
#define PP   80
#define KK   161
#define NITER 100
#define LAMB 0.1f

#define CODE_SZ (NB*KK*FF)          // 2,060,800
#define D_OFF   CODE_SZ
#define R_OFF   (CODE_SZ + TT*KK)

// ws float layout:
// [1] = wn^2 accumulator; [16..79] = ssq partials (64 k_build blocks)
// [WSA1..] A1 image (D):   [Mt1:3][kt:6][h:2][512] f16 = 9216 floats
// [WSA2..] A2 image (D^T): [Mt2:6][kt:3][h:2][512] f16 = 9216 floats
#define WSA1 128
#define WSA2 (128 + 9216)

typedef _Float16 half8 __attribute__((ext_vector_type(8)));
typedef float f32x4  __attribute__((ext_vector_type(4)));
typedef float f32x16 __attribute__((ext_vector_type(16)));
#define MFMA_16(A,B,C) __builtin_amdgcn_mfma_f32_16x16x32_f16(A,B,C,0,0,0)
#define MFMA_32(A,B,C) __builtin_amdgcn_mfma_f32_32x32x16_f16(A,B,C,0,0,0)

// ---------------------------------------------------------------------------
// K1 (grid 64): build D (blk0 -> d_out), ssq partials -> ws[16+b], pack f16
// hi/lo MFMA A-operand images for D (GEMM1 16x16x32) and D^T (GEMM2 32x32x16).
__global__ __launch_bounds__(256) void k_build(const float* __restrict__ rr,
                                               const float* __restrict__ th,
                                               float* __restrict__ out,
                                               float* __restrict__ ws) {
    __shared__ float Dl[TT*KK];
    __shared__ float red[256];
    int tid = threadIdx.x, b = blockIdx.x;
    for (int e = tid; e < TT*KK; e += 256) {
        int t = e / KK, k = e % KK;
        float v;
        if (k == 0) v = 1.f;
        else if (k <= PP) { int p = k - 1;     v = powf(rr[p], (float)t) * cosf((float)t * th[p]); }
        else              { int p = k - 1 - PP; v = powf(rr[p], (float)t) * sinf((float)t * th[p]); }
        Dl[e] = v;
        if (b == 0) out[D_OFF + e] = v;
    }
    __syncthreads();
    float ssq = 0.f;
    for (int p = b*256 + tid; p < KK*KK; p += 64*256) {
        int k1 = p / KK, k2 = p % KK;
        float s = 0.f;
        for (int t = 0; t < TT; ++t) s += Dl[t*KK + k1] * Dl[t*KK + k2];
        ssq += s * s;
    }
    red[tid] = ssq;
    __syncthreads();
    for (int off = 128; off > 0; off >>= 1) {
        if (tid < off) red[tid] += red[tid + off];
        __syncthreads();
    }
    if (tid == 0) { ws[16 + b] = red[0]; if (b == 0) ws[1] = 0.f; }

    // A1: lane l holds A[m=l&15][k=8*(l>>4)+i] per 16x16x32 tile
    _Float16* a1 = (_Float16*)(ws + WSA1);
    for (int e = b*256 + tid; e < 3*6*2*512; e += 64*256) {
        int fp = e & 511, r = e >> 9;       // r = (Mt1*6+kt)*2 + h
        int h = r & 1, mk = r >> 1;
        int l = fp >> 3, i = fp & 7;
        int t = (mk / 6) * 16 + (l & 15);
        int j = (mk % 6) * 32 + ((l >> 4) << 3) + i;
        float v = (t < TT && j < KK) ? Dl[t*KK + j] : 0.f;
        _Float16 hi = (_Float16)v;
        a1[e] = h ? (_Float16)(v - (float)hi) : hi;
    }
    // A2 (D^T): lane l holds A[m=l&31][k=8*(l>>5)+i] per 32x32x16 tile
    _Float16* a2 = (_Float16*)(ws + WSA2);
    for (int e = b*256 + tid; e < 6*3*2*512; e += 64*256) {
        int fp = e & 511, r = e >> 9;       // r = (Mt2*3+kt)*2 + h
        int h = r & 1, mk = r >> 1;
        int l = fp >> 3, i = fp & 7;
        int m = (mk / 3) * 32 + (l & 31);
        int t = (mk % 3) * 16 + ((l >> 5) << 3) + i;
        float v = (m < KK && t < TT) ? Dl[t*KK + m] : 0.f;
        _Float16 hi = (_Float16)v;
        a2[e] = h ? (_Float16)(v - (float)hi) : hi;
    }
}

// ---------------------------------------------------------------------------
// K2: fused FISTA (R6 structure, chain-split MFMA). grid 256 (one n per
// block), 768 threads = 12 waves, all waves on one 64-col problem.
// 2-term quantized GEMMs: y,z stored f16-hi in LDS; D hi+lo in registers
// (exact for f16-quantized operand).
// GEMM1 (z = D y): 16x16x32, wave = (Mt1 = w>>2, nt1 = w&3), 4x3 MFMA chains.
// GEMM2 (w = D^T z): 32x32x16, wave = (Mt2 = w>>1, nh = w&1), 2x3 chains.
// Head: DtY via GEMM2 over f16(x). Tails: ph0 wnorm, ph1 reconst.
__global__ __launch_bounds__(768, 3) void k_fista(float* __restrict__ ws,
                                                  const float* __restrict__ x,
                                                  float* __restrict__ out,
                                                  int phase) {
    __shared__ _Float16 Ys[4*6*512];   // 24,576 B: [nt16:4][kt32:6][512]
    __shared__ _Float16 Zs[2*3*512];   //  6,144 B: [nh:2][kt16:3][512]
    int tid = threadIdx.x;
    int w = tid >> 6, l = tid & 63;
    int n = blockIdx.x;

    // ---- stage x -> Zs (f16 hi, GEMM2 B-frag image, k-dim = t)
    const float* xb = x + n*TT*FF;
    for (int e = tid; e < 3072; e += 768) {
        int t = e >> 6, c64 = e & 63;
        float v = (t < TT && c64 < FF) ? xb[t*FF + c64] : 0.f;
        int nh = c64 >> 5, c = c64 & 31;
        int kt = t >> 4, kk = t & 15;
        int ofs = ((((kk >> 3) << 5) + c) << 3) + (kk & 7);
        Zs[((nh*3 + kt) << 9) + ofs] = (_Float16)v;
    }

    float ssum = 0.f;
    #pragma unroll
    for (int i = 0; i < 64; ++i) ssum += ws[16 + i];
    float linv = rsqrtf(ssum);

    int Mt1 = w >> 2, nt1 = w & 3;     // GEMM1 role
    int Mt2 = w >> 1, nh  = w & 1;     // GEMM2 role
    const _Float16* a1g = (const _Float16*)(ws + WSA1);
    const _Float16* a2g = (const _Float16*)(ws + WSA2);
    half8 a1[6][2], a2[3][2];
    #pragma unroll
    for (int kt = 0; kt < 6; ++kt)
        #pragma unroll
        for (int h = 0; h < 2; ++h)
            a1[kt][h] = *(const half8*)(a1g + ((((Mt1*6 + kt)*2 + h) << 9) + (l << 3)));
    #pragma unroll
    for (int kt = 0; kt < 3; ++kt)
        #pragma unroll
        for (int h = 0; h < 2; ++h)
            a2[kt][h] = *(const half8*)(a2g + ((((Mt2*3 + kt)*2 + h) << 9) + (l << 3)));
    __syncthreads();

    // ---- head GEMM2: acc = D^T @ f16(x)  (c-vector, registers only)
    f32x16 acA, acB;
    #pragma unroll
    for (int r = 0; r < 16; ++r) { acA[r] = 0.f; acB[r] = 0.f; }
    #pragma unroll
    for (int kt = 0; kt < 3; ++kt) {
        half8 bh = *(const half8*)&Zs[((nh*3 + kt) << 9) + (l << 3)];
        acA = MFMA_32(a2[kt][0], bh, acA);
        acB = MFMA_32(a2[kt][1], bh, acB);
    }

    int cl = l & 15, q = l >> 4;       // GEMM1 C addressing
    int nloc = l & 31, s5 = l >> 5;    // GEMM2 C addressing
    int nt16 = nh*2 + (nloc >> 4);
    int fcol = nh*32 + nloc;           // global f of owned columns
    int zofs = ((((q >> 1) << 5) + (nt1 & 1)*16 + cl) << 3) + ((q & 1) << 2);
    int znh = nt1 >> 1;
    float cm[4][4], cp[4][4], xo[4][4], yo[4][4];

    // ---- peeled iteration 0: x1 = shrink(c), y1 = x1
    {
        float wl0 = LAMB * linv;
        float fac = 0.f;
        if (phase) fac = (float)KK * LAMB * linv * rsqrtf(ws[1]);
        #pragma unroll
        for (int gq = 0; gq < 4; ++gq) {
            int k0 = Mt2*32 + 8*gq + 4*s5;
            union { unsigned long long u; _Float16 hh[4]; } yh;
            #pragma unroll
            for (int j = 0; j < 4; ++j) {
                int k = k0 + j;
                float cv = 0.f, wl = 0.f;
                if (k < KK && fcol < FF) {
                    cv = linv * (acA[gq*4 + j] + acB[gq*4 + j]);
                    if (phase) {
                        float prev = out[(size_t)n*KK*FF + k*FF + fcol];
                        wl = fac / (fabsf(prev) + 0.01f);
                    } else wl = wl0;
                }
                cm[gq][j] = cv - wl; cp[gq][j] = cv + wl;
                float xn = fmaxf(0.f, cm[gq][j]) + fminf(0.f, cp[gq][j]);
                xo[gq][j] = xn; yo[gq][j] = xn;
                yh.hh[j] = (_Float16)xn;
            }
            int yofs = ((gq*16 + cl) << 3) + (s5 << 2);
            *(unsigned long long*)&Ys[((nt16*6 + Mt2) << 9) + yofs] = yh.u;
        }
    }
    __syncthreads();

    float t_old = 0.5f * (1.f + sqrtf(5.f));
    for (int it = 1; it < NITER; ++it) {
        // ---- GEMM1: z(Mt1, nt1) = D @ f16(y)  (4 independent 3-chains)
        f32x4 za = {0.f,0.f,0.f,0.f}, zb = {0.f,0.f,0.f,0.f};
        f32x4 zc = {0.f,0.f,0.f,0.f}, zd = {0.f,0.f,0.f,0.f};
        #pragma unroll
        for (int kt = 0; kt < 6; ++kt) {
            half8 bh = *(const half8*)&Ys[((nt1*6 + kt) << 9) + (l << 3)];
            if (kt & 1) { zc = MFMA_16(a1[kt][0], bh, zc); zd = MFMA_16(a1[kt][1], bh, zd); }
            else        { za = MFMA_16(a1[kt][0], bh, za); zb = MFMA_16(a1[kt][1], bh, zb); }
        }
        f32x4 zz = (za + zb) + (zc + zd);
        {
            union { unsigned long long u; _Float16 hh[4]; } ph;
            #pragma unroll
            for (int r = 0; r < 4; ++r) ph.hh[r] = (_Float16)zz[r];
            *(unsigned long long*)&Zs[((znh*3 + Mt1) << 9) + zofs] = ph.u;
        }
        __syncthreads();

        // ---- GEMM2: acc(Mt2, nh) = D^T @ f16(z)  (2 independent 3-chains)
        #pragma unroll
        for (int r = 0; r < 16; ++r) { acA[r] = 0.f; acB[r] = 0.f; }
        #pragma unroll
        for (int kt = 0; kt < 3; ++kt) {
            half8 bh = *(const half8*)&Zs[((nh*3 + kt) << 9) + (l << 3)];
            acA = MFMA_32(a2[kt][0], bh, acA);
            acB = MFMA_32(a2[kt][1], bh, acB);
        }
        // ---- epilogue: shrink + momentum, rebuild y image (f16 hi)
        float t_new = 0.5f * (1.f + sqrtf(1.f + 4.f*t_old*t_old));
        float beta = (t_old - 1.f) / t_new;
        t_old = t_new;
        #pragma unroll
        for (int gq = 0; gq < 4; ++gq) {
            union { unsigned long long u; _Float16 hh[4]; } yh;
            #pragma unroll
            for (int j = 0; j < 4; ++j) {
                float av = acA[gq*4 + j] + acB[gq*4 + j];
                float ay = fmaf(-linv, av, yo[gq][j]);
                float xn = fmaxf(0.f, ay + cm[gq][j]) + fminf(0.f, ay + cp[gq][j]);
                float yn = fmaf(beta, xn - xo[gq][j], xn);
                xo[gq][j] = xn; yo[gq][j] = yn;
                yh.hh[j] = (_Float16)yn;
            }
            int yofs = ((gq*16 + cl) << 3) + (s5 << 2);
            *(unsigned long long*)&Ys[((nt16*6 + Mt2) << 9) + yofs] = yh.u;
        }
        __syncthreads();
    }

    // ---- store final code
    #pragma unroll
    for (int gq = 0; gq < 4; ++gq) {
        int k0 = Mt2*32 + 8*gq + 4*s5;
        #pragma unroll
        for (int j = 0; j < 4; ++j) {
            int k = k0 + j;
            if (k < KK && fcol < FF)
                out[(size_t)n*KK*FF + k*FF + fcol] = xo[gq][j];
        }
    }

    if (!phase) {
        // ---- fused wnorm
        float s = 0.f;
        #pragma unroll
        for (int gq = 0; gq < 4; ++gq) {
            int k0 = Mt2*32 + 8*gq + 4*s5;
            #pragma unroll
            for (int j = 0; j < 4; ++j) {
                if (k0 + j < KK && fcol < FF) {
                    float wn = 1.f / (fabsf(xo[gq][j]) + 0.01f);
                    s += wn * wn;
                }
            }
        }
        #pragma unroll
        for (int off = 32; off > 0; off >>= 1) s += __shfl_down(s, off);
        float* red = (float*)Zs;
        if (l == 0) red[w] = s;
        __syncthreads();
        if (tid == 0) {
            float t = 0.f;
            #pragma unroll
            for (int i = 0; i < 12; ++i) t += red[i];
            atomicAdd(&ws[1], t);
        }
    } else {
        // ---- fused reconst: f16(code) into Ys, GEMM1 pass, store
        #pragma unroll
        for (int gq = 0; gq < 4; ++gq) {
            union { unsigned long long u; _Float16 hh[4]; } yh;
            #pragma unroll
            for (int j = 0; j < 4; ++j) yh.hh[j] = (_Float16)xo[gq][j];
            int yofs = ((gq*16 + cl) << 3) + (s5 << 2);
            *(unsigned long long*)&Ys[((nt16*6 + Mt2) << 9) + yofs] = yh.u;
        }
        __syncthreads();
        f32x4 za = {0.f,0.f,0.f,0.f}, zb = {0.f,0.f,0.f,0.f};
        #pragma unroll
        for (int kt = 0; kt < 6; ++kt) {
            half8 bh = *(const half8*)&Ys[((nt1*6 + kt) << 9) + (l << 3)];
            za = MFMA_16(a1[kt][0], bh, za);
            zb = MFMA_16(a1[kt][1], bh, zb);
        }
        f32x4 zz = za + zb;
        int fcol2 = nt1*16 + cl;
        #pragma unroll
        for (int r = 0; r < 4; ++r) {
            int t = Mt1*16 + q*4 + r;
            if (t < TT && fcol2 < FF)
                out[R_OFF + (size_t)n*TT*FF + t*FF + fcol2] = zz[r];
        }
    }
}

// ---------------------------------------------------------------------------
extern "C" void kernel_launch(void* const* d_in, const int* in_sizes, int n_in,
                              void* d_out, int out_size, void* d_ws, size_t ws_size,
                              hipStream_t stream) {
    const float* x  = (const float*)d_in[0];
    const float* rr = (const float*)d_in[1];
    const float* th = (const float*)d_in[2];
    float* out = (float*)d_out;
    float* ws  = (float*)d_ws;

    hipLaunchKernelGGL(k_build, dim3(64),  dim3(256), 0, stream, rr, th, out, ws);
    hipLaunchKernelGGL(k_fista, dim3(NB),  dim3(768), 0, stream, ws, x, out, 0);
    hipLaunchKernelGGL(k_fista, dim3(NB),  dim3(768), 0, stream, ws, x, out, 1);
}

// Round 10
// 550.773 us; speedup vs baseline: 1.1493x; 1.0301x over previous
//
#include <hip/hip_runtime.h>
#include <math.h>

// Problem constants
#define NB   256
#define TT   36
#define FF   50
#define PP   80
#define KK   161
#define NITER 100
#define LAMB 0.1f

#define CODE_SZ (NB*KK*FF)          // 2,060,800
#define D_OFF   CODE_SZ
#define R_OFF   (CODE_SZ + TT*KK)

// ws float layout:
// [1] = wn^2 accumulator; [16..79] = ssq partials (64 k_build blocks)
// [WSA1..] A1 image (D):   [Mt1:3][kt:6][h:2][512] f16 = 9216 floats
// [WSA2..] A2 image (D^T): [Mt2:6][kt:3][h:2][512] f16 = 9216 floats
#define WSA1 128
#define WSA2 (128 + 9216)

typedef _Float16 half8  __attribute__((ext_vector_type(8)));
typedef _Float16 half16v __attribute__((ext_vector_type(16)));
typedef float f32x4  __attribute__((ext_vector_type(4)));
typedef float f32x16 __attribute__((ext_vector_type(16)));
#define MFMA_16(A,B,C) __builtin_amdgcn_mfma_f32_16x16x32_f16(A,B,C,0,0,0)
#define MFMA_32(A,B,C) __builtin_amdgcn_mfma_f32_32x32x16_f16(A,B,C,0,0,0)

// ---------------------------------------------------------------------------
// K1 (grid 64): build D (blk0 -> d_out), ssq partials -> ws[16+b], pack f16
// hi/lo MFMA A-operand images for D (GEMM1 16x16x32) and D^T (GEMM2 32x32x16).
__global__ __launch_bounds__(256) void k_build(const float* __restrict__ rr,
                                               const float* __restrict__ th,
                                               float* __restrict__ out,
                                               float* __restrict__ ws) {
    __shared__ float Dl[TT*KK];
    __shared__ float red[256];
    int tid = threadIdx.x, b = blockIdx.x;
    for (int e = tid; e < TT*KK; e += 256) {
        int t = e / KK, k = e % KK;
        float v;
        if (k == 0) v = 1.f;
        else if (k <= PP) { int p = k - 1;     v = powf(rr[p], (float)t) * cosf((float)t * th[p]); }
        else              { int p = k - 1 - PP; v = powf(rr[p], (float)t) * sinf((float)t * th[p]); }
        Dl[e] = v;
        if (b == 0) out[D_OFF + e] = v;
    }
    __syncthreads();
    float ssq = 0.f;
    for (int p = b*256 + tid; p < KK*KK; p += 64*256) {
        int k1 = p / KK, k2 = p % KK;
        float s = 0.f;
        for (int t = 0; t < TT; ++t) s += Dl[t*KK + k1] * Dl[t*KK + k2];
        ssq += s * s;
    }
    red[tid] = ssq;
    __syncthreads();
    for (int off = 128; off > 0; off >>= 1) {
        if (tid < off) red[tid] += red[tid + off];
        __syncthreads();
    }
    if (tid == 0) { ws[16 + b] = red[0]; if (b == 0) ws[1] = 0.f; }

    // A1: lane l holds A[m=l&15][k=8*(l>>4)+i] per 16x16x32 tile
    _Float16* a1 = (_Float16*)(ws + WSA1);
    for (int e = b*256 + tid; e < 3*6*2*512; e += 64*256) {
        int fp = e & 511, r = e >> 9;       // r = (Mt1*6+kt)*2 + h
        int h = r & 1, mk = r >> 1;
        int l = fp >> 3, i = fp & 7;
        int t = (mk / 6) * 16 + (l & 15);
        int j = (mk % 6) * 32 + ((l >> 4) << 3) + i;
        float v = (t < TT && j < KK) ? Dl[t*KK + j] : 0.f;
        _Float16 hi = (_Float16)v;
        a1[e] = h ? (_Float16)(v - (float)hi) : hi;
    }
    // A2 (D^T): lane l holds A[m=l&31][k=8*(l>>5)+i] per 32x32x16 tile
    _Float16* a2 = (_Float16*)(ws + WSA2);
    for (int e = b*256 + tid; e < 6*3*2*512; e += 64*256) {
        int fp = e & 511, r = e >> 9;       // r = (Mt2*3+kt)*2 + h
        int h = r & 1, mk = r >> 1;
        int l = fp >> 3, i = fp & 7;
        int m = (mk / 3) * 32 + (l & 31);
        int t = (mk % 3) * 16 + ((l >> 5) << 3) + i;
        float v = (m < KK && t < TT) ? Dl[t*KK + m] : 0.f;
        _Float16 hi = (_Float16)v;
        a2[e] = h ? (_Float16)(v - (float)hi) : hi;
    }
}

// ---------------------------------------------------------------------------
// K2: fused FISTA (R6 structure, register-neutral trims). grid 256 (one n
// per block), 768 threads = 12 waves, all waves on one 64-col problem.
// 2-term quantized GEMMs: y,z stored f16-hi in LDS; D hi+lo in registers
// (exact for f16-quantized operand).
// GEMM1 (z = D y): 16x16x32, wave = (Mt1 = w>>2, nt1 = w&3), 4x3 MFMA chains
//   (za..zd share lifetimes with acc -> no net register growth).
// GEMM2 (w = D^T z): 32x32x16, wave = (Mt2 = w>>1, nh = w&1), single chain.
// Shrink state: cv fp32 (16 regs) + wl f16 (8 regs); x = v - med3(v,-wl,wl).
// Head: DtY via GEMM2 over f16(x). Tails: ph0 wnorm, ph1 reconst.
__global__ __launch_bounds__(768, 3) void k_fista(float* __restrict__ ws,
                                                  const float* __restrict__ x,
                                                  float* __restrict__ out,
                                                  int phase) {
    __shared__ _Float16 Ys[4*6*512];   // 24,576 B: [nt16:4][kt32:6][512]
    __shared__ _Float16 Zs[2*3*512];   //  6,144 B: [nh:2][kt16:3][512]
    int tid = threadIdx.x;
    int w = tid >> 6, l = tid & 63;
    int n = blockIdx.x;

    // ---- stage x -> Zs (f16 hi, GEMM2 B-frag image, k-dim = t)
    const float* xb = x + n*TT*FF;
    for (int e = tid; e < 3072; e += 768) {
        int t = e >> 6, c64 = e & 63;
        float v = (t < TT && c64 < FF) ? xb[t*FF + c64] : 0.f;
        int nh = c64 >> 5, c = c64 & 31;
        int kt = t >> 4, kk = t & 15;
        int ofs = ((((kk >> 3) << 5) + c) << 3) + (kk & 7);
        Zs[((nh*3 + kt) << 9) + ofs] = (_Float16)v;
    }

    float ssum = 0.f;
    #pragma unroll
    for (int i = 0; i < 64; ++i) ssum += ws[16 + i];
    float linv = rsqrtf(ssum);

    int Mt1 = w >> 2, nt1 = w & 3;     // GEMM1 role
    int Mt2 = w >> 1, nh  = w & 1;     // GEMM2 role
    const _Float16* a1g = (const _Float16*)(ws + WSA1);
    const _Float16* a2g = (const _Float16*)(ws + WSA2);
    half8 a1[6][2], a2[3][2];
    #pragma unroll
    for (int kt = 0; kt < 6; ++kt)
        #pragma unroll
        for (int h = 0; h < 2; ++h)
            a1[kt][h] = *(const half8*)(a1g + ((((Mt1*6 + kt)*2 + h) << 9) + (l << 3)));
    #pragma unroll
    for (int kt = 0; kt < 3; ++kt)
        #pragma unroll
        for (int h = 0; h < 2; ++h)
            a2[kt][h] = *(const half8*)(a2g + ((((Mt2*3 + kt)*2 + h) << 9) + (l << 3)));
    __syncthreads();

    // ---- head GEMM2: acc = D^T @ f16(x)  (c-vector, registers only)
    f32x16 acc;
    #pragma unroll
    for (int r = 0; r < 16; ++r) acc[r] = 0.f;
    #pragma unroll
    for (int kt = 0; kt < 3; ++kt) {
        half8 bh = *(const half8*)&Zs[((nh*3 + kt) << 9) + (l << 3)];
        acc = MFMA_32(a2[kt][0], bh, acc);
        acc = MFMA_32(a2[kt][1], bh, acc);
    }

    int cl = l & 15, q = l >> 4;       // GEMM1 C addressing
    int nloc = l & 31, s5 = l >> 5;    // GEMM2 C addressing
    int nt16 = nh*2 + (nloc >> 4);
    int fcol = nh*32 + nloc;           // global f of owned columns
    int zofs = ((((q >> 1) << 5) + (nt1 & 1)*16 + cl) << 3) + ((q & 1) << 2);
    int znh = nt1 >> 1;
    float cv[4][4], xo[4][4], yo[4][4];
    half16v wlh;

    // ---- peeled iteration 0: x1 = shrink(c), y1 = x1
    {
        float wl0 = LAMB * linv;
        float fac = 0.f;
        if (phase) fac = (float)KK * LAMB * linv * rsqrtf(ws[1]);
        #pragma unroll
        for (int gq = 0; gq < 4; ++gq) {
            int k0 = Mt2*32 + 8*gq + 4*s5;
            union { unsigned long long u; _Float16 hh[4]; } yh;
            #pragma unroll
            for (int j = 0; j < 4; ++j) {
                int k = k0 + j;
                float c_ = 0.f, wl = 0.f;
                if (k < KK && fcol < FF) {
                    c_ = linv * acc[gq*4 + j];
                    if (phase) {
                        float prev = out[(size_t)n*KK*FF + k*FF + fcol];
                        wl = fac / (fabsf(prev) + 0.01f);
                    } else wl = wl0;
                }
                cv[gq][j] = c_;
                wlh[gq*4 + j] = (_Float16)wl;
                float wlq = (float)wlh[gq*4 + j];
                float xn = c_ - fminf(fmaxf(c_, -wlq), wlq);
                xo[gq][j] = xn; yo[gq][j] = xn;
                yh.hh[j] = (_Float16)xn;
            }
            int yofs = ((gq*16 + cl) << 3) + (s5 << 2);
            *(unsigned long long*)&Ys[((nt16*6 + Mt2) << 9) + yofs] = yh.u;
        }
    }
    __syncthreads();

    float t_old = 0.5f * (1.f + sqrtf(5.f));
    for (int it = 1; it < NITER; ++it) {
        // ---- GEMM1: z(Mt1, nt1) = D @ f16(y)  (4 independent 3-chains;
        //      za..zd lifetimes end before acc is rebuilt -> reg-shared)
        f32x4 za = {0.f,0.f,0.f,0.f}, zb = {0.f,0.f,0.f,0.f};
        f32x4 zc = {0.f,0.f,0.f,0.f}, zd = {0.f,0.f,0.f,0.f};
        #pragma unroll
        for (int kt = 0; kt < 6; ++kt) {
            half8 bh = *(const half8*)&Ys[((nt1*6 + kt) << 9) + (l << 3)];
            if (kt & 1) { zc = MFMA_16(a1[kt][0], bh, zc); zd = MFMA_16(a1[kt][1], bh, zd); }
            else        { za = MFMA_16(a1[kt][0], bh, za); zb = MFMA_16(a1[kt][1], bh, zb); }
        }
        f32x4 zz = (za + zb) + (zc + zd);
        {
            union { unsigned long long u; _Float16 hh[4]; } ph;
            #pragma unroll
            for (int r = 0; r < 4; ++r) ph.hh[r] = (_Float16)zz[r];
            *(unsigned long long*)&Zs[((znh*3 + Mt1) << 9) + zofs] = ph.u;
        }
        __syncthreads();

        // ---- GEMM2: acc(Mt2, nh) = D^T @ f16(z)  (single chain, no acB)
        #pragma unroll
        for (int r = 0; r < 16; ++r) acc[r] = 0.f;
        #pragma unroll
        for (int kt = 0; kt < 3; ++kt) {
            half8 bh = *(const half8*)&Zs[((nh*3 + kt) << 9) + (l << 3)];
            acc = MFMA_32(a2[kt][0], bh, acc);
            acc = MFMA_32(a2[kt][1], bh, acc);
        }
        // ---- epilogue: v = y - linv*w + c; x = v - med3(v,-wl,wl); momentum
        float t_new = 0.5f * (1.f + sqrtf(1.f + 4.f*t_old*t_old));
        float beta = (t_old - 1.f) / t_new;
        t_old = t_new;
        #pragma unroll
        for (int gq = 0; gq < 4; ++gq) {
            union { unsigned long long u; _Float16 hh[4]; } yh;
            #pragma unroll
            for (int j = 0; j < 4; ++j) {
                float wl = (float)wlh[gq*4 + j];
                float ay = fmaf(-linv, acc[gq*4 + j], yo[gq][j]);
                float v = ay + cv[gq][j];
                float xn = v - fminf(fmaxf(v, -wl), wl);
                float yn = fmaf(beta, xn - xo[gq][j], xn);
                xo[gq][j] = xn; yo[gq][j] = yn;
                yh.hh[j] = (_Float16)yn;
            }
            int yofs = ((gq*16 + cl) << 3) + (s5 << 2);
            *(unsigned long long*)&Ys[((nt16*6 + Mt2) << 9) + yofs] = yh.u;
        }
        __syncthreads();
    }

    // ---- store final code
    #pragma unroll
    for (int gq = 0; gq < 4; ++gq) {
        int k0 = Mt2*32 + 8*gq + 4*s5;
        #pragma unroll
        for (int j = 0; j < 4; ++j) {
            int k = k0 + j;
            if (k < KK && fcol < FF)
                out[(size_t)n*KK*FF + k*FF + fcol] = xo[gq][j];
        }
    }

    if (!phase) {
        // ---- fused wnorm
        float s = 0.f;
        #pragma unroll
        for (int gq = 0; gq < 4; ++gq) {
            int k0 = Mt2*32 + 8*gq + 4*s5;
            #pragma unroll
            for (int j = 0; j < 4; ++j) {
                if (k0 + j < KK && fcol < FF) {
                    float wn = 1.f / (fabsf(xo[gq][j]) + 0.01f);
                    s += wn * wn;
                }
            }
        }
        #pragma unroll
        for (int off = 32; off > 0; off >>= 1) s += __shfl_down(s, off);
        float* red = (float*)Zs;
        if (l == 0) red[w] = s;
        __syncthreads();
        if (tid == 0) {
            float t = 0.f;
            #pragma unroll
            for (int i = 0; i < 12; ++i) t += red[i];
            atomicAdd(&ws[1], t);
        }
    } else {
        // ---- fused reconst: f16(code) into Ys, GEMM1 pass, store
        #pragma unroll
        for (int gq = 0; gq < 4; ++gq) {
            union { unsigned long long u; _Float16 hh[4]; } yh;
            #pragma unroll
            for (int j = 0; j < 4; ++j) yh.hh[j] = (_Float16)xo[gq][j];
            int yofs = ((gq*16 + cl) << 3) + (s5 << 2);
            *(unsigned long long*)&Ys[((nt16*6 + Mt2) << 9) + yofs] = yh.u;
        }
        __syncthreads();
        f32x4 za = {0.f,0.f,0.f,0.f}, zb = {0.f,0.f,0.f,0.f};
        #pragma unroll
        for (int kt = 0; kt < 6; ++kt) {
            half8 bh = *(const half8*)&Ys[((nt1*6 + kt) << 9) + (l << 3)];
            za = MFMA_16(a1[kt][0], bh, za);
            zb = MFMA_16(a1[kt][1], bh, zb);
        }
        f32x4 zz = za + zb;
        int fcol2 = nt1*16 + cl;
        #pragma unroll
        for (int r = 0; r < 4; ++r) {
            int t = Mt1*16 + q*4 + r;
            if (t < TT && fcol2 < FF)
                out[R_OFF + (size_t)n*TT*FF + t*FF + fcol2] = zz[r];
        }
    }
}

// ---------------------------------------------------------------------------
extern "C" void kernel_launch(void* const* d_in, const int* in_sizes, int n_in,
                              void* d_out, int out_size, void* d_ws, size_t ws_size,
                              hipStream_t stream) {
    const float* x  = (const float*)d_in[0];
    const float* rr = (const float*)d_in[1];
    const float* th = (const float*)d_in[2];
    float* out = (float*)d_out;
    float* ws  = (float*)d_ws;

    hipLaunchKernelGGL(k_build, dim3(64),  dim3(256), 0, stream, rr, th, out, ws);
    hipLaunchKernelGGL(k_fista, dim3(NB),  dim3(768), 0, stream, ws, x, out, 0);
    hipLaunchKernelGGL(k_fista, dim3(NB),  dim3(768), 0, stream, ws, x, out, 1);
}